// Round 1
// baseline (341.637 us; speedup 1.0000x reference)
//
#include <hip/hip_runtime.h>

#define H 128
#define MAXD 64

// ---------------------------------------------------------------------------
// Stage-1 tables: Qc/Knc/Vnc/KEc (32xH), tmpA/tmpB (16xH), tmpC (4xH), uc (32)
// One block (128 threads) per output row; thread j computes element j.
// ---------------------------------------------------------------------------
__global__ __launch_bounds__(128) void k_tables1(
    const float* __restrict__ emb_v, const float* __restrict__ emb_b,
    const float* __restrict__ emb_e, const float* __restrict__ emb_s,
    const float* __restrict__ Wq, const float* __restrict__ Wk,
    const float* __restrict__ Wv, const float* __restrict__ Wek,
    const float* __restrict__ Wcf,
    const float* __restrict__ gW1, const float* __restrict__ gb1,
    const float* __restrict__ gW2, const float* __restrict__ gb2,
    float* __restrict__ Qc, float* __restrict__ Knc, float* __restrict__ Vnc,
    float* __restrict__ KEc, float* __restrict__ tmpA, float* __restrict__ tmpB,
    float* __restrict__ tmpC, float* __restrict__ uc)
{
    int b = blockIdx.x;
    int j = threadIdx.x;
    if (b < 32) {                       // Qc[c] = emb_v[c] @ Wq
        int c = b;
        float acc = 0.f;
        for (int k = 0; k < H; ++k) acc += emb_v[c*H + k] * Wq[k*H + j];
        Qc[c*H + j] = acc;
    } else if (b < 64) {                // Knc[c] = emb_v[c] @ Wk
        int c = b - 32;
        float acc = 0.f;
        for (int k = 0; k < H; ++k) acc += emb_v[c*H + k] * Wk[k*H + j];
        Knc[c*H + j] = acc;
    } else if (b < 96) {                // Vnc[c] = emb_v[c] @ Wv
        int c = b - 64;
        float acc = 0.f;
        for (int k = 0; k < H; ++k) acc += emb_v[c*H + k] * Wv[k*H + j];
        Vnc[c*H + j] = acc;
    } else if (b < 128) {               // KEc[c] = emb_v[c]@Wk + emb_b[c]@Wek
        int c = b - 96;
        float acc = 0.f;
        for (int k = 0; k < H; ++k)
            acc += emb_v[c*H + k] * Wk[k*H + j] + emb_b[c*H + k] * Wek[k*H + j];
        KEc[c*H + j] = acc;
    } else if (b < 144) {               // tmpA[c] = emb_e[c] @ Wcf[0:128]
        int c = b - 128;
        float acc = 0.f;
        for (int k = 0; k < H; ++k) acc += emb_e[c*H + k] * Wcf[k*H + j];
        tmpA[c*H + j] = acc;
    } else if (b < 160) {               // tmpB[c] = emb_e[c] @ Wcf[128:256]
        int c = b - 144;
        float acc = 0.f;
        for (int k = 0; k < H; ++k) acc += emb_e[c*H + k] * Wcf[(H + k)*H + j];
        tmpB[c*H + j] = acc;
    } else if (b < 164) {               // tmpC[c] = emb_s[c] @ Wcf[256:384]
        int c = b - 160;
        float acc = 0.f;
        for (int k = 0; k < H; ++k) acc += emb_s[c*H + k] * Wcf[(2*H + k)*H + j];
        tmpC[c*H + j] = acc;
    } else {                            // uc[c] = sigmoid(relu(emb_v[c]@gW1+gb1)@gW2+gb2)
        int c = b - 164;
        float acc = 0.f;
        for (int k = 0; k < H; ++k) acc += emb_v[c*H + k] * gW1[k*H + j];
        float hj = fmaxf(acc + gb1[j], 0.f) * gW2[j];
        __shared__ float sb[2];
        float v = hj;
        for (int off = 32; off; off >>= 1) v += __shfl_xor(v, off);
        if ((threadIdx.x & 63) == 0) sb[threadIdx.x >> 6] = v;
        __syncthreads();
        if (threadIdx.x == 0) {
            float x = sb[0] + sb[1] + gb2[0];
            uc[c] = 1.f / (1.f + expf(-x));
        }
    }
}

// ---------------------------------------------------------------------------
// Stage-2 tables: Ae/Be (16xH), Cs (4xH), Ldot (32x32), Lself (32)
// ---------------------------------------------------------------------------
__global__ __launch_bounds__(128) void k_tables2(
    const float* __restrict__ Wev,
    const float* __restrict__ tmpA, const float* __restrict__ tmpB,
    const float* __restrict__ tmpC,
    const float* __restrict__ Qc, const float* __restrict__ Knc,
    const float* __restrict__ KEc,
    float* __restrict__ Ae, float* __restrict__ Be, float* __restrict__ Cs,
    float* __restrict__ Ldot, float* __restrict__ Lself)
{
    int b = blockIdx.x;
    int j = threadIdx.x;
    const float scale = 1.0f / 11.313708498984761f;   // 1/sqrt(128)
    if (b < 16) {
        float acc = 0.f;
        for (int k = 0; k < H; ++k) acc += tmpA[b*H + k] * Wev[k*H + j];
        Ae[b*H + j] = acc;
    } else if (b < 32) {
        int c = b - 16;
        float acc = 0.f;
        for (int k = 0; k < H; ++k) acc += tmpB[c*H + k] * Wev[k*H + j];
        Be[c*H + j] = acc;
    } else if (b < 36) {
        int c = b - 32;
        float acc = 0.f;
        for (int k = 0; k < H; ++k) acc += tmpC[c*H + k] * Wev[k*H + j];
        Cs[c*H + j] = acc;
    } else {                            // Ldot row a + Lself[a]
        int a = b - 36;
        float qj = Qc[a*H + j];
        __shared__ float sb[2];
        for (int bb = 0; bb < 32; ++bb) {
            float v = qj * KEc[bb*H + j];
            for (int off = 32; off; off >>= 1) v += __shfl_xor(v, off);
            if ((threadIdx.x & 63) == 0) sb[threadIdx.x >> 6] = v;
            __syncthreads();
            if (threadIdx.x == 0) Ldot[a*32 + bb] = (sb[0] + sb[1]) * scale;
            __syncthreads();
        }
        float v = qj * Knc[a*H + j];
        for (int off = 32; off; off >>= 1) v += __shfl_xor(v, off);
        if ((threadIdx.x & 63) == 0) sb[threadIdx.x >> 6] = v;
        __syncthreads();
        if (threadIdx.x == 0) Lself[a] = (sb[0] + sb[1]) * scale;
    }
}

// ---------------------------------------------------------------------------
__global__ __launch_bounds__(256) void k_nodecode(
    const int* __restrict__ ns, int* __restrict__ node_code, int N)
{
    int t = blockIdx.x * 256 + threadIdx.x;
    if (t < N)
        node_code[t] = 2 * (ns[4*t] + 2*ns[4*t+1] + 4*ns[4*t+2] + 8*ns[4*t+3]);
}

// ---------------------------------------------------------------------------
// Per-edge: ecode, packed (csrc|ec|ecrev|sc) scattered into adjacency by slot.
// ---------------------------------------------------------------------------
__global__ __launch_bounds__(256) void k_edgeprep(
    const int* __restrict__ edge_states, const float* __restrict__ scalars,
    const int* __restrict__ src_idx, const int* __restrict__ dst_idx,
    const int* __restrict__ rev_idx, const int* __restrict__ slot_idx,
    const int* __restrict__ self_loop, const int* __restrict__ node_code,
    int* __restrict__ ecode, int* __restrict__ adjP, int* __restrict__ deg, int E)
{
    int e = blockIdx.x * 256 + threadIdx.x;
    if (e >= E) return;
    int ec = edge_states[4*e] + 2*edge_states[4*e+1] + 4*edge_states[4*e+2] + 8*edge_states[4*e+3];
    ecode[e] = ec;
    int rv = rev_idx[e];
    int er = edge_states[4*rv] + 2*edge_states[4*rv+1] + 4*edge_states[4*rv+2] + 8*edge_states[4*rv+3];
    float se = scalars[e];
    int sn = src_idx[e], dn = dst_idx[e];
    float ss = scalars[self_loop[sn]];
    float rs = scalars[self_loop[dn]];
    int rlx  = (se < rs) ? 1 : 0;
    int rlxd = ((ss + se) < rs) ? 1 : 0;
    int sc = rlx + 2 * rlxd;
    int cs = node_code[sn];
    int packed = cs | (ec << 5) | (er << 9) | (sc << 13);
    int sl = slot_idx[e];
    if (sl < MAXD) adjP[(size_t)dn * MAXD + sl] = packed;
    atomicAdd(&deg[dn], 1);
}

// ---------------------------------------------------------------------------
// One wave per node: logits from tables, entmax15/softmax/sparsemax blend,
// hard straight-through selection, aggregate selected V rows.
// ---------------------------------------------------------------------------
__global__ __launch_bounds__(256) void k_attn(
    const int* __restrict__ node_code, const int* __restrict__ deg,
    const int* __restrict__ adjP, const float* __restrict__ uc,
    const float* __restrict__ Lself, const float* __restrict__ Ldot,
    const float* __restrict__ Vnc, const float* __restrict__ Ae,
    const float* __restrict__ Be, const float* __restrict__ Cs,
    const float* __restrict__ emb_v,
    float* __restrict__ agg, float* __restrict__ node_out, int N)
{
    __shared__ float sortbuf[4][64];
    int lane = threadIdx.x & 63;
    int w = threadIdx.x >> 6;
    int n = blockIdx.x * 4 + w;
    bool valid = n < N;
    int cn = 0, d = 0;
    if (valid) {
        cn = node_code[n];
        d = deg[n];
        if (d > 63) d = 63;
    }

    // slot logit per lane: lane 0 = self slot, lanes 1..d = edges, rest masked
    float z = -1e9f;
    int padj = 0;
    if (valid) {
        if (lane == 0) z = Lself[cn];
        else if (lane <= d) {
            padj = adjP[(size_t)n * MAXD + lane - 1];
            z = Ldot[cn * 32 + (padj & 31)];
        }
    }

    // rank-sort (descending, lane tie-break) -> sorted via LDS scatter
    int rank = 0;
    for (int jj = 0; jj < 64; ++jj) {
        float zj = __shfl(z, jj);
        rank += (zj > z) || (zj == z && jj < lane);
    }
    sortbuf[w][rank] = z;
    __syncthreads();
    float zs = sortbuf[w][lane];

    // inclusive scans of zs and zs^2 over the wave
    float cz = zs, cz2 = zs * zs;
    for (int off = 1; off < 64; off <<= 1) {
        float a = __shfl_up(cz, off);
        float b = __shfl_up(cz2, off);
        if (lane >= off) { cz += a; cz2 += b; }
    }

    // entmax-1.5
    float kk = (float)(lane + 1);
    float mz = cz / kk, mz2 = cz2 / kk;
    float discr = fmaxf(mz * mz - mz2 + 1.0f / kk, 0.0f);
    float tau_c = mz - sqrtf(discr);
    int kidx = __popcll(__ballot(zs > tau_c));
    float tau15 = __shfl(tau_c, kidx - 1);
    float r15 = fmaxf(z - tau15, 0.0f);
    float p15 = r15 * r15;

    // sparsemax
    int ksp = __popcll(__ballot(kk * zs > cz - 1.0f));
    float csk = __shfl(cz, ksp - 1);
    float tausp = (csk - 1.0f) / (float)ksp;
    float psp = fmaxf(z - tausp, 0.0f);

    // softmax
    float zmax = __shfl(zs, 0);
    float ex = expf(z - zmax);
    float s = ex;
    for (int off = 32; off; off >>= 1) s += __shfl_xor(s, off);
    float psoft = ex / s;

    // blend by u (wave-uniform)
    float uu = uc[cn];
    float probs;
    if (uu <= 0.5f) { float wl = 2.0f * uu;         probs = (1.0f - wl) * psoft + wl * p15; }
    else            { float wh = (uu - 0.5f) * 2.0f; probs = (1.0f - wh) * p15 + wh * psp; }

    // straight-through hard attention: attn = is_sel / (count + 1e-9)
    unsigned long long msk = __ballot(probs > 1e-6f);
    int cnt = __popcll(msk);
    float scale = 1.0f / ((float)cnt + 1e-9f);

    // accumulate selected V rows; lane = feature dim (handles j and j+64)
    float a0 = 0.f, a1 = 0.f;
    unsigned long long mk = msk;
    while (mk) {
        int sl = __ffsll(mk) - 1;
        mk &= mk - 1;
        if (sl == 0) {
            a0 += Vnc[cn*H + lane];
            a1 += Vnc[cn*H + 64 + lane];
        } else {
            int p = __shfl(padj, sl);
            int cs = p & 31, ec = (p >> 5) & 15, er = (p >> 9) & 15, sc = (p >> 13) & 3;
            a0 += Vnc[cs*H + lane]      + Ae[ec*H + lane]      + Be[er*H + lane]      + Cs[sc*H + lane];
            a1 += Vnc[cs*H + 64 + lane] + Ae[ec*H + 64 + lane] + Be[er*H + 64 + lane] + Cs[sc*H + 64 + lane];
        }
    }
    a0 *= scale; a1 *= scale;

    if (valid) {
        agg[(size_t)n*H + lane]      = a0;
        agg[(size_t)n*H + 64 + lane] = a1;
        node_out[(size_t)n*H + lane]      = emb_v[cn*H + lane]      + a0;
        node_out[(size_t)n*H + 64 + lane] = emb_v[cn*H + 64 + lane] + a1;
    }
}

// ---------------------------------------------------------------------------
// edge_out[e] = emb_e[ecode[e]] + agg[dst[e]]   (float4 vectorized)
// ---------------------------------------------------------------------------
__global__ __launch_bounds__(256) void k_edgeout(
    const int* __restrict__ ecode, const int* __restrict__ dst_idx,
    const float* __restrict__ agg, const float* __restrict__ emb_e,
    float* __restrict__ out_edge, int E)
{
    long long t = (long long)blockIdx.x * 256 + threadIdx.x;
    if (t >= (long long)E * 32) return;
    int e = (int)(t >> 5);
    int q = (int)(t & 31);
    int ec = ecode[e];
    int dn = dst_idx[e];
    float4 ve = ((const float4*)(emb_e + (size_t)ec * H))[q];
    float4 va = ((const float4*)(agg + (size_t)dn * H))[q];
    float4 r;
    r.x = ve.x + va.x; r.y = ve.y + va.y; r.z = ve.z + va.z; r.w = ve.w + va.w;
    ((float4*)(out_edge + (size_t)e * H))[q] = r;
}

// ---------------------------------------------------------------------------
extern "C" void kernel_launch(void* const* d_in, const int* in_sizes, int n_in,
                              void* d_out, int out_size, void* d_ws, size_t ws_size,
                              hipStream_t stream)
{
    const int*   node_states = (const int*)d_in[0];
    const int*   edge_states = (const int*)d_in[1];
    const float* scalars     = (const float*)d_in[2];
    const int*   src_idx     = (const int*)d_in[3];
    const int*   dst_idx     = (const int*)d_in[4];
    const int*   rev_idx     = (const int*)d_in[5];
    const int*   slot_idx    = (const int*)d_in[6];
    const int*   self_loop   = (const int*)d_in[7];
    // d_in[8] = max_deg (unused: padded slots provably contribute zero)
    const float* emb_v = (const float*)d_in[9];
    const float* emb_b = (const float*)d_in[10];
    const float* emb_e = (const float*)d_in[11];
    const float* emb_s = (const float*)d_in[12];
    const float* Wq  = (const float*)d_in[13];
    const float* Wk  = (const float*)d_in[14];
    const float* Wv  = (const float*)d_in[15];
    const float* Wek = (const float*)d_in[16];
    const float* Wev = (const float*)d_in[17];
    const float* Wcf = (const float*)d_in[18];
    const float* gW1 = (const float*)d_in[19];
    const float* gb1 = (const float*)d_in[20];
    const float* gW2 = (const float*)d_in[21];
    const float* gb2 = (const float*)d_in[22];

    const int N = in_sizes[0] / 4;
    const int E = in_sizes[1] / 4;

    // workspace layout (floats, then ints); total ~17 MB
    float* ws   = (float*)d_ws;
    float* Qc   = ws; ws += 32*H;
    float* Knc  = ws; ws += 32*H;
    float* Vnc  = ws; ws += 32*H;
    float* KEc  = ws; ws += 32*H;
    float* tmpA = ws; ws += 16*H;
    float* tmpB = ws; ws += 16*H;
    float* tmpC = ws; ws += 4*H;
    float* Ae   = ws; ws += 16*H;
    float* Be   = ws; ws += 16*H;
    float* Cs   = ws; ws += 4*H;
    float* uc   = ws; ws += 32;
    float* Lself= ws; ws += 32;
    float* Ldot = ws; ws += 32*32;
    float* agg  = ws; ws += (size_t)N*H;
    int* node_code = (int*)ws;
    int* ecode = node_code + N;
    int* adjP  = ecode + E;
    int* deg   = adjP + (size_t)N * MAXD;

    hipMemsetAsync(deg, 0, (size_t)N * sizeof(int), stream);

    k_tables1<<<196, 128, 0, stream>>>(emb_v, emb_b, emb_e, emb_s, Wq, Wk, Wv, Wek,
                                       Wcf, gW1, gb1, gW2, gb2,
                                       Qc, Knc, Vnc, KEc, tmpA, tmpB, tmpC, uc);
    k_tables2<<<68, 128, 0, stream>>>(Wev, tmpA, tmpB, tmpC, Qc, Knc, KEc,
                                      Ae, Be, Cs, Ldot, Lself);
    k_nodecode<<<(N + 255) / 256, 256, 0, stream>>>(node_states, node_code, N);
    k_edgeprep<<<(E + 255) / 256, 256, 0, stream>>>(edge_states, scalars, src_idx,
                                                    dst_idx, rev_idx, slot_idx,
                                                    self_loop, node_code,
                                                    ecode, adjP, deg, E);
    k_attn<<<(N + 3) / 4, 256, 0, stream>>>(node_code, deg, adjP, uc, Lself, Ldot,
                                            Vnc, Ae, Be, Cs, emb_v,
                                            agg, (float*)d_out, N);
    long long tot = (long long)E * 32;
    k_edgeout<<<(int)((tot + 255) / 256), 256, 0, stream>>>(ecode, dst_idx, agg, emb_e,
                                                            (float*)d_out + (size_t)N * H, E);
}